// Round 2
// baseline (533.205 us; speedup 1.0000x reference)
//
#include <hip/hip_runtime.h>
#include <cstdint>
#include <cstddef>

// GAT layer, N=8192, F=128.
// Pipeline: k1 (Wh=h@W -> WhT fp16, init M2) -> k1b (s1,s2, atomicMax M2)
//        -> k1c (per-row/col exp factors) -> k2 (fused mask+softmax+PV via fp16 MFMA).
// Softmax trick: p_ij = adj ? exp(leaky(s1+s2) - c_r) : 0, with c_r an upper bound
// (shift-invariant => exact). exp factors out per branch: no transcendentals in k2.
// R1 fix: ep (f32x4* into EF) must advance 32 per 64-j tile (was 8) — unit bug.

#define NROW 8192
#define FDIM 128

typedef _Float16 f16;
typedef f16 f16x8 __attribute__((ext_vector_type(8)));
typedef float f32x4 __attribute__((ext_vector_type(4)));

// workspace byte offsets
#define WS_WHT 0u                          // f16 WhT[128][8192]  : 2 MiB
#define WS_S12 (2u * 1024u * 1024u)        // float2 s12[8192]    : 64 KiB
#define WS_RC  (WS_S12 + 64u * 1024u)      // float4 RC[8192]     : 128 KiB (tau,k1,k2,-)
#define WS_EF  (WS_RC + 128u * 1024u)      // float2 EF[8192]     : 64 KiB (exp(s2),exp(.2 s2))
#define WS_M2  (WS_EF + 64u * 1024u)       // unsigned M2 key

// ---------------- k1: Wh = h @ W, store WhT fp16 (transposed, [f][row]) ----------------
__global__ __launch_bounds__(256) void k1_wh(const float* __restrict__ h,
                                             const float* __restrict__ W,
                                             f16* __restrict__ WhT,
                                             unsigned* __restrict__ M2key) {
  __shared__ float hT[128 * 36];  // hT[k][r], stride 36 (16B-aligned rows, broadcast reads)
  const int t = (int)threadIdx.x;
  const int rb = (int)blockIdx.x * 32;
  if (blockIdx.x == 0 && t == 0) *M2key = 0u;  // init for k1b's encoded atomicMax
  const f32x4* hv = (const f32x4*)(h + (size_t)rb * FDIM);
#pragma unroll
  for (int i = 0; i < 4; ++i) {
    int fidx = t + i * 256;
    f32x4 v = hv[fidx];
    int e0 = fidx * 4;
    int r = e0 >> 7, k = e0 & 127;
    hT[(k + 0) * 36 + r] = v[0];
    hT[(k + 1) * 36 + r] = v[1];
    hT[(k + 2) * 36 + r] = v[2];
    hT[(k + 3) * 36 + r] = v[3];
  }
  __syncthreads();
  const int f = t & 127, rh = t >> 7;
  f32x4 z = {0.f, 0.f, 0.f, 0.f};
  f32x4 acc0 = z, acc1 = z, acc2 = z, acc3 = z;
  for (int k = 0; k < 128; ++k) {
    float w = W[k * FDIM + f];
    const f32x4* hp = (const f32x4*)(hT + k * 36 + rh * 16);
    acc0 += hp[0] * w;
    acc1 += hp[1] * w;
    acc2 += hp[2] * w;
    acc3 += hp[3] * w;
  }
  union { f16 hx[16]; uint4 u[2]; } pk;
#pragma unroll
  for (int q = 0; q < 4; ++q) {
    pk.hx[0 + q]  = (f16)acc0[q];
    pk.hx[4 + q]  = (f16)acc1[q];
    pk.hx[8 + q]  = (f16)acc2[q];
    pk.hx[12 + q] = (f16)acc3[q];
  }
  uint4* dst = (uint4*)(WhT + (size_t)f * NROW + rb + rh * 16);
  dst[0] = pk.u[0];
  dst[1] = pk.u[1];
}

// ---------------- k1b: s1,s2 per row; global max(s2) via encoded atomicMax ----------------
__global__ __launch_bounds__(256) void k1b_s(const f16* __restrict__ WhT,
                                             const float* __restrict__ a,
                                             float2* __restrict__ s12,
                                             unsigned* __restrict__ M2key) {
  int r = (int)blockIdx.x * 256 + (int)threadIdx.x;
  float s1 = 0.f, s2 = 0.f;
  for (int f = 0; f < 128; ++f) {
    float w = (float)WhT[(size_t)f * NROW + r];
    s1 = fmaf(w, a[f], s1);
    s2 = fmaf(w, a[128 + f], s2);
  }
  s12[r] = make_float2(s1, s2);
  float mx = s2;
#pragma unroll
  for (int off = 32; off; off >>= 1) mx = fmaxf(mx, __shfl_xor(mx, off, 64));
  if ((threadIdx.x & 63) == 0) {
    unsigned key = __float_as_uint(mx);
    key = (key & 0x80000000u) ? ~key : (key | 0x80000000u);  // monotone encoding
    atomicMax(M2key, key);
  }
}

// ---------------- k1c: per-index exp factors ----------------
__global__ __launch_bounds__(256) void k1c_prep(const float2* __restrict__ s12,
                                                const unsigned* __restrict__ M2key,
                                                float4* __restrict__ RC,
                                                float2* __restrict__ EF) {
  int j = (int)blockIdx.x * 256 + (int)threadIdx.x;
  unsigned key = *M2key;
  float M2 = (key & 0x80000000u) ? __uint_as_float(key ^ 0x80000000u)
                                 : __uint_as_float(~key);
  float2 s = s12[j];
  float c = s.x + M2;
  c = fmaxf(c, 0.2f * c);  // leaky_relu(s1 + max s2) >= all row scores => p <= 1
  RC[j] = make_float4(__expf(-s.x), __expf(s.x - c), __expf(0.2f * s.x - c), 0.f);
  EF[j] = make_float2(__expf(s.y), __expf(0.2f * s.y));
}

// ---------------- k2: fused masked-softmax @ Wh, fp16 MFMA ----------------
// grid 256 x 512 threads. WG = 32 rows, loops all 8192 j in 64-wide tiles.
// wave w: mh=w&1 (row half), kh=(w>>1)&1 (k half of tile), nh=w>>2 (feature half).
__global__ __launch_bounds__(512) void k2_main(const int* __restrict__ adj,
                                               const f16* __restrict__ WhT,
                                               const float4* __restrict__ RC,
                                               const float* __restrict__ EF,
                                               float* __restrict__ out) {
  __shared__ __align__(16) f16 whbuf[2][8192];  // 2 x [128 f][64 j] fp16, XOR-chunk swizzled
  __shared__ float dpart[2][32];

  const int tid = (int)threadIdx.x;
  const int L = tid & 63, w = tid >> 6;
  const int mh = w & 1, kh = (w >> 1) & 1, nh = w >> 2;
  const int m = L & 15, kg = L >> 4;
  const int rb = (int)blockIdx.x * 32;
  const int rloc = mh * 16 + m;
  const int row = rb + rloc;
  const int jo = kh * 32 + kg * 8;  // lane's j-offset within a 64-tile

  const float4 rc = RC[row];
  const float tau = rc.x, kap1 = rc.y, kap2 = rc.z;

  // staging map: 2 x 16B per thread per tile; LDS chunk c holds global chunk c^(f&7)
  const int sf0 = tid >> 3;       // f row 0..63 (second issue: +64)
  const int scc = tid & 7;        // LDS chunk
  const int stl0 = sf0 * 64 + scc * 8;
  const f16* gp0 = WhT + (size_t)sf0 * NROW + (size_t)((scc ^ (sf0 & 7)) * 8);
  const f16* gp1 = gp0 + (size_t)64 * NROW;

  const int* ap = adj + (size_t)row * NROW + jo;
  const f32x4* ep = (const f32x4*)(EF + 2 * jo);

  // prefetch tile 0
  uint4 S0 = *(const uint4*)gp0;
  uint4 S1 = *(const uint4*)gp1;
  int4 A0 = *(const int4*)ap;
  int4 A1 = *(const int4*)(ap + 4);
  f32x4 Ev0 = ep[0], Ev1 = ep[1], Ev2 = ep[2], Ev3 = ep[3];

  f32x4 z = {0.f, 0.f, 0.f, 0.f};
  f32x4 acc[4] = {z, z, z, z};
  float dloc = 0.f;

  const int bofs = (nh * 64 + m) * 64 + (((kh * 4 + kg) ^ (m & 7)) * 8);

  for (int t = 0; t < 128; ++t) {
    f16* wb = &whbuf[t & 1][0];
    // stage current Wh tile (prefetched regs -> LDS)
    *(uint4*)(wb + stl0) = S0;
    *(uint4*)(wb + stl0 + 4096) = S1;

    // build A-fragment (P values) for current tile; exact A-operand layout
    f16x8 af;
    {
      float p;
      p = (Ev0[0] > tau) ? Ev0[0] * kap1 : Ev0[1] * kap2; p = (A0.x > 0) ? p : 0.f; dloc += p; af[0] = (f16)p;
      p = (Ev0[2] > tau) ? Ev0[2] * kap1 : Ev0[3] * kap2; p = (A0.y > 0) ? p : 0.f; dloc += p; af[1] = (f16)p;
      p = (Ev1[0] > tau) ? Ev1[0] * kap1 : Ev1[1] * kap2; p = (A0.z > 0) ? p : 0.f; dloc += p; af[2] = (f16)p;
      p = (Ev1[2] > tau) ? Ev1[2] * kap1 : Ev1[3] * kap2; p = (A0.w > 0) ? p : 0.f; dloc += p; af[3] = (f16)p;
      p = (Ev2[0] > tau) ? Ev2[0] * kap1 : Ev2[1] * kap2; p = (A1.x > 0) ? p : 0.f; dloc += p; af[4] = (f16)p;
      p = (Ev2[2] > tau) ? Ev2[2] * kap1 : Ev2[3] * kap2; p = (A1.y > 0) ? p : 0.f; dloc += p; af[5] = (f16)p;
      p = (Ev3[0] > tau) ? Ev3[0] * kap1 : Ev3[1] * kap2; p = (A1.z > 0) ? p : 0.f; dloc += p; af[6] = (f16)p;
      p = (Ev3[2] > tau) ? Ev3[2] * kap1 : Ev3[3] * kap2; p = (A1.w > 0) ? p : 0.f; dloc += p; af[7] = (f16)p;
    }

    __syncthreads();  // staging visible; also fences previous tile's buffer reuse

    // prefetch next tile right after the barrier (latency hides under MFMA phase)
    int adv = (t < 127) ? 1 : 0;
    ap += adv * 64;
    ep += adv * 32;   // 64 j * 2 floats = 128 floats = 32 f32x4 (R1 fix: was 8)
    gp0 += adv * 64;
    gp1 += adv * 64;
    uint4 Sn0 = *(const uint4*)gp0;
    uint4 Sn1 = *(const uint4*)gp1;
    int4 An0 = *(const int4*)ap;
    int4 An1 = *(const int4*)(ap + 4);
    f32x4 En0 = ep[0], En1 = ep[1], En2 = ep[2], En3 = ep[3];

    // B fragments from LDS (swizzle-corrected), 4 n-tiles of 16
    const f16* wbB = wb + bofs;
    f16x8 b0 = *(const f16x8*)(wbB);
    f16x8 b1 = *(const f16x8*)(wbB + 1024);
    f16x8 b2 = *(const f16x8*)(wbB + 2048);
    f16x8 b3 = *(const f16x8*)(wbB + 3072);
    acc[0] = __builtin_amdgcn_mfma_f32_16x16x32_f16(af, b0, acc[0], 0, 0, 0);
    acc[1] = __builtin_amdgcn_mfma_f32_16x16x32_f16(af, b1, acc[1], 0, 0, 0);
    acc[2] = __builtin_amdgcn_mfma_f32_16x16x32_f16(af, b2, acc[2], 0, 0, 0);
    acc[3] = __builtin_amdgcn_mfma_f32_16x16x32_f16(af, b3, acc[3], 0, 0, 0);

    S0 = Sn0; S1 = Sn1; A0 = An0; A1 = An1;
    Ev0 = En0; Ev1 = En1; Ev2 = En2; Ev3 = En3;
  }

  // denominator: reduce over kg lanes, combine kh halves via LDS
  dloc += __shfl_xor(dloc, 16, 64);
  dloc += __shfl_xor(dloc, 32, 64);
  if (nh == 0 && kg == 0) dpart[kh][rloc] = dloc;
  __syncthreads();

  // kh-split accumulator reduction through LDS (overlays whbuf; padded stride 18)
  float* red = (float*)&whbuf[0][0];
  const int q4 = (nh * 2 + mh) * 4;
  if (kh == 1) {
#pragma unroll
    for (int nt = 0; nt < 4; ++nt)
#pragma unroll
      for (int e = 0; e < 4; ++e)
        red[(q4 + nt) * 288 + (kg * 4 + e) * 18 + m] = acc[nt][e];
  }
  __syncthreads();
  if (kh == 0) {
    float inv0[4];
#pragma unroll
    for (int e = 0; e < 4; ++e) {
      int rr = mh * 16 + kg * 4 + e;
      inv0[e] = 1.0f / (dpart[0][rr] + dpart[1][rr]);
    }
#pragma unroll
    for (int nt = 0; nt < 4; ++nt) {
#pragma unroll
      for (int e = 0; e < 4; ++e) {
        float x = (acc[nt][e] + red[(q4 + nt) * 288 + (kg * 4 + e) * 18 + m]) * inv0[e];
        float r = x > 0.f ? x : expm1f(x);  // elu, alpha=1
        out[(size_t)(rb + mh * 16 + kg * 4 + e) * FDIM + nh * 64 + nt * 16 + m] = r;
      }
    }
  }
}

extern "C" void kernel_launch(void* const* d_in, const int* in_sizes, int n_in,
                              void* d_out, int out_size, void* d_ws, size_t ws_size,
                              hipStream_t stream) {
  const float* h = (const float*)d_in[0];
  const int* adj = (const int*)d_in[1];
  const float* W = (const float*)d_in[2];
  const float* a = (const float*)d_in[3];
  float* out = (float*)d_out;
  char* ws = (char*)d_ws;
  f16* WhT = (f16*)(ws + WS_WHT);
  float2* s12 = (float2*)(ws + WS_S12);
  float4* RC = (float4*)(ws + WS_RC);
  float2* EF = (float2*)(ws + WS_EF);
  unsigned* M2 = (unsigned*)(ws + WS_M2);

  k1_wh<<<dim3(256), dim3(256), 0, stream>>>(h, W, WhT, M2);
  k1b_s<<<dim3(32), dim3(256), 0, stream>>>(WhT, a, s12, M2);
  k1c_prep<<<dim3(32), dim3(256), 0, stream>>>(s12, M2, RC, EF);
  k2_main<<<dim3(256), dim3(512), 0, stream>>>(adj, WhT, RC, (const float*)EF, out);
}

// Round 3
// 449.827 us; speedup vs baseline: 1.1854x; 1.1854x over previous
//
#include <hip/hip_runtime.h>
#include <cstdint>
#include <cstddef>

// GAT layer, N=8192, F=128.  Round 3: barrier-free k2.
// k1  : Wh = h@W -> WhT fp16 [f][row] (for k1b) + Bpack (MFMA B-frag order, for k2)
// k1b : s1,s2 per row (f-split, 128 blocks); global max(s2) via encoded atomicMax
// k1c : per-index exp factors (tau,kap1,kap2 per row; E=exp(s2),F=exp(.2*s2) per col)
// k2  : 32x32x16 f16 MFMA, 1 wave = 32 rows x 128 f, j split into S chunks,
//       NO LDS / NO barriers; adj+EF prefetched 1 iter ahead, B 1KB coalesced loads.
// k3  : combine S partials, ELU, store.
// R2 post-mortem: old k2 was lockstep-barrier latency-bound (MfmaUtil 2.7%, hbm 7.5%).

#define NROW 8192
#define FDIM 128

typedef _Float16 f16;
typedef f16 f16x8 __attribute__((ext_vector_type(8)));
typedef float f32x4 __attribute__((ext_vector_type(4)));
typedef float f32x16 __attribute__((ext_vector_type(16)));

// workspace byte offsets
#define WS_WHT 0u                            // f16 WhT[128][8192]        : 2 MiB
#define WS_BP  (2u*1024u*1024u)              // f16 Bpack[512][4][64][8]  : 2 MiB
#define WS_S12 (4u*1024u*1024u)              // float2 s12[8192]          : 64 KiB
#define WS_RC  (WS_S12 + 64u*1024u)          // float4 RC[8192]           : 128 KiB
#define WS_EF  (WS_RC + 128u*1024u)          // float2 EF[8192]           : 64 KiB
#define WS_M2  (WS_EF + 64u*1024u)           // unsigned M2 key (pad 4K)
#define WS_PWS (WS_M2 + 4u*1024u)            // float Pws[S][8192][128]   : S*4 MiB
// Dws = WS_PWS + S*4MiB : float Dws[S][8192]

// ---------------- k1: Wh = h @ W; write WhT fp16 and Bpack ----------------
__global__ __launch_bounds__(256) void k1_wh(const float* __restrict__ h,
                                             const float* __restrict__ W,
                                             f16* __restrict__ WhT,
                                             f16* __restrict__ Bp,
                                             unsigned* __restrict__ M2key) {
  __shared__ float hT[128 * 36];  // hT[k][r], stride 36
  const int t = (int)threadIdx.x;
  const int rb = (int)blockIdx.x * 32;
  if (blockIdx.x == 0 && t == 0) *M2key = 0u;
  const f32x4* hv = (const f32x4*)(h + (size_t)rb * FDIM);
#pragma unroll
  for (int i = 0; i < 4; ++i) {
    int fidx = t + i * 256;
    f32x4 v = hv[fidx];
    int e0 = fidx * 4;
    int r = e0 >> 7, k = e0 & 127;
    hT[(k + 0) * 36 + r] = v[0];
    hT[(k + 1) * 36 + r] = v[1];
    hT[(k + 2) * 36 + r] = v[2];
    hT[(k + 3) * 36 + r] = v[3];
  }
  __syncthreads();
  const int f = t & 127, rh = t >> 7;
  f32x4 z = {0.f, 0.f, 0.f, 0.f};
  f32x4 acc0 = z, acc1 = z, acc2 = z, acc3 = z;
  for (int k = 0; k < 128; ++k) {
    float w = W[k * FDIM + f];
    const f32x4* hp = (const f32x4*)(hT + k * 36 + rh * 16);
    acc0 += hp[0] * w;
    acc1 += hp[1] * w;
    acc2 += hp[2] * w;
    acc3 += hp[3] * w;
  }
  union { f16 hx[16]; uint4 u[2]; } pk;
#pragma unroll
  for (int q = 0; q < 4; ++q) {
    pk.hx[0 + q]  = (f16)acc0[q];   // hx[i] = Wh[rb + rh*16 + i][f]
    pk.hx[4 + q]  = (f16)acc1[q];
    pk.hx[8 + q]  = (f16)acc2[q];
    pk.hx[12 + q] = (f16)acc3[q];
  }
  // WhT [f][row]
  uint4* dst = (uint4*)(WhT + (size_t)f * NROW + rb + rh * 16);
  dst[0] = pk.u[0];
  dst[1] = pk.u[1];
  // Bpack[jt=j/16][nt=f/32][lane=(f&31)+32*kb][e] = Wh[jt*16+kb*8+e][f]
  // jt for this thread = bid*2 + rh; kb=0 -> hx[0..7], kb=1 -> hx[8..15]
  f16* bdst = Bp + ((size_t)((blockIdx.x * 2 + rh) * 4 + (f >> 5)) * 64 + (f & 31)) * 8;
  *(uint4*)bdst = pk.u[0];
  *(uint4*)(bdst + 256) = pk.u[1];   // +32 lanes * 8
}

// ---------------- k1b: s1,s2 per row (f-split x4); encoded atomicMax M2 ----------------
__global__ __launch_bounds__(256) void k1b_s(const f16* __restrict__ WhT,
                                             const float* __restrict__ a,
                                             float2* __restrict__ s12,
                                             unsigned* __restrict__ M2key) {
  __shared__ float part[2][4][64];
  const int l = (int)threadIdx.x & 63;
  const int fc = (int)threadIdx.x >> 6;
  const int r = (int)blockIdx.x * 64 + l;
  float s1 = 0.f, s2 = 0.f;
  for (int f = fc * 32; f < fc * 32 + 32; ++f) {
    float w = (float)WhT[(size_t)f * NROW + r];
    s1 = fmaf(w, a[f], s1);
    s2 = fmaf(w, a[128 + f], s2);
  }
  part[0][fc][l] = s1;
  part[1][fc][l] = s2;
  __syncthreads();
  if (fc == 0) {
    s1 = part[0][0][l] + part[0][1][l] + part[0][2][l] + part[0][3][l];
    s2 = part[1][0][l] + part[1][1][l] + part[1][2][l] + part[1][3][l];
    s12[r] = make_float2(s1, s2);
    float mx = s2;
#pragma unroll
    for (int off = 32; off; off >>= 1) mx = fmaxf(mx, __shfl_xor(mx, off, 64));
    if (l == 0) {
      unsigned key = __float_as_uint(mx);
      key = (key & 0x80000000u) ? ~key : (key | 0x80000000u);
      atomicMax(M2key, key);
    }
  }
}

// ---------------- k1c: per-index exp factors ----------------
__global__ __launch_bounds__(256) void k1c_prep(const float2* __restrict__ s12,
                                                const unsigned* __restrict__ M2key,
                                                float4* __restrict__ RC,
                                                float2* __restrict__ EF) {
  int j = (int)blockIdx.x * 256 + (int)threadIdx.x;
  unsigned key = *M2key;
  float M2 = (key & 0x80000000u) ? __uint_as_float(key ^ 0x80000000u)
                                 : __uint_as_float(~key);
  float2 s = s12[j];
  float c = s.x + M2;
  c = fmaxf(c, 0.2f * c);  // upper bound on all row scores => p <= 1
  RC[j] = make_float4(__expf(-s.x), __expf(s.x - c), __expf(0.2f * s.x - c), 0.f);
  EF[j] = make_float2(__expf(s.y), __expf(0.2f * s.y));
}

// ---------------- k2: barrier-free fused masked-softmax @ Wh ----------------
// wave wid: rg = wid&255 (32-row group), c = wid>>8 (j chunk of jspan).
// lane: m = L&31 (row), kb = L>>5 (k-half). Per 32-j iter: 2 A-frags, 8 MFMA.
__global__ __launch_bounds__(256) void k2_main(const int* __restrict__ adj,
                                               const f16* __restrict__ Bp,
                                               const float4* __restrict__ RC,
                                               const float* __restrict__ EF,
                                               float* __restrict__ Pws,
                                               float* __restrict__ Dws,
                                               int jspan) {
  const int tid = (int)threadIdx.x;
  const int L = tid & 63, w = tid >> 6;
  const int wid = (int)blockIdx.x * 4 + w;
  const int rg = wid & 255;
  const int c = wid >> 8;
  const int rb = rg * 32;
  const int m = L & 31, kb = L >> 5;
  const int row = rb + m;
  const int j0 = c * jspan;
  const int niter = jspan >> 5;

  const float4 rc = RC[row];
  const float tau = rc.x, kap1 = rc.y, kap2 = rc.z;

  const int* ap = adj + (size_t)row * NROW + j0 + kb * 8;
  const f32x4* ep = (const f32x4*)(EF + 2 * (j0 + kb * 8));
  const f16* bp = Bp + (size_t)(j0 >> 4) * 2048 + L * 8;  // tile stride 2048 f16

  // prefetch iter 0: adj (4 x int4 = 32 j's for this lane's rows) + EF pairs
  int4 A0 = *(const int4*)ap;
  int4 A1 = *(const int4*)(ap + 4);
  int4 A2 = *(const int4*)(ap + 16);
  int4 A3 = *(const int4*)(ap + 20);
  f32x4 E0 = ep[0], E1 = ep[1], E2 = ep[2], E3 = ep[3];
  f32x4 E4 = ep[8], E5 = ep[9], E6 = ep[10], E7 = ep[11];

  f32x16 zz = {0.f};
  f32x16 acc[4] = {zz, zz, zz, zz};
  float dloc = 0.f;

  for (int it = 0; it < niter; ++it) {
    // B loads first (L2 ~200cyc hides under the score build below)
    const f16* bt = bp + (size_t)it * 4096;
    f16x8 B00 = *(const f16x8*)(bt);
    f16x8 B01 = *(const f16x8*)(bt + 512);
    f16x8 B02 = *(const f16x8*)(bt + 1024);
    f16x8 B03 = *(const f16x8*)(bt + 1536);
    f16x8 B10 = *(const f16x8*)(bt + 2048);
    f16x8 B11 = *(const f16x8*)(bt + 2560);
    f16x8 B12 = *(const f16x8*)(bt + 3072);
    f16x8 B13 = *(const f16x8*)(bt + 3584);

    // score build: p = adj ? exp(leaky(s1+s2)-c) : 0, branch-factored, no exp
    f16x8 af0, af1;
    {
      float p;
      p = (E0[0] > tau) ? E0[0] * kap1 : E0[1] * kap2; p = (A0.x > 0) ? p : 0.f; dloc += p; af0[0] = (f16)p;
      p = (E0[2] > tau) ? E0[2] * kap1 : E0[3] * kap2; p = (A0.y > 0) ? p : 0.f; dloc += p; af0[1] = (f16)p;
      p = (E1[0] > tau) ? E1[0] * kap1 : E1[1] * kap2; p = (A0.z > 0) ? p : 0.f; dloc += p; af0[2] = (f16)p;
      p = (E1[2] > tau) ? E1[2] * kap1 : E1[3] * kap2; p = (A0.w > 0) ? p : 0.f; dloc += p; af0[3] = (f16)p;
      p = (E2[0] > tau) ? E2[0] * kap1 : E2[1] * kap2; p = (A1.x > 0) ? p : 0.f; dloc += p; af0[4] = (f16)p;
      p = (E2[2] > tau) ? E2[2] * kap1 : E2[3] * kap2; p = (A1.y > 0) ? p : 0.f; dloc += p; af0[5] = (f16)p;
      p = (E3[0] > tau) ? E3[0] * kap1 : E3[1] * kap2; p = (A1.z > 0) ? p : 0.f; dloc += p; af0[6] = (f16)p;
      p = (E3[2] > tau) ? E3[2] * kap1 : E3[3] * kap2; p = (A1.w > 0) ? p : 0.f; dloc += p; af0[7] = (f16)p;
      p = (E4[0] > tau) ? E4[0] * kap1 : E4[1] * kap2; p = (A2.x > 0) ? p : 0.f; dloc += p; af1[0] = (f16)p;
      p = (E4[2] > tau) ? E4[2] * kap1 : E4[3] * kap2; p = (A2.y > 0) ? p : 0.f; dloc += p; af1[1] = (f16)p;
      p = (E5[0] > tau) ? E5[0] * kap1 : E5[1] * kap2; p = (A2.z > 0) ? p : 0.f; dloc += p; af1[2] = (f16)p;
      p = (E5[2] > tau) ? E5[2] * kap1 : E5[3] * kap2; p = (A2.w > 0) ? p : 0.f; dloc += p; af1[3] = (f16)p;
      p = (E6[0] > tau) ? E6[0] * kap1 : E6[1] * kap2; p = (A3.x > 0) ? p : 0.f; dloc += p; af1[4] = (f16)p;
      p = (E6[2] > tau) ? E6[2] * kap1 : E6[3] * kap2; p = (A3.y > 0) ? p : 0.f; dloc += p; af1[5] = (f16)p;
      p = (E7[0] > tau) ? E7[0] * kap1 : E7[1] * kap2; p = (A3.z > 0) ? p : 0.f; dloc += p; af1[6] = (f16)p;
      p = (E7[2] > tau) ? E7[2] * kap1 : E7[3] * kap2; p = (A3.w > 0) ? p : 0.f; dloc += p; af1[7] = (f16)p;
    }

    // prefetch next iter's adj/EF (HBM latency hides across the MFMA + next build)
    int adv = (it < niter - 1) ? 1 : 0;
    ap += adv * 32;
    ep += adv * 16;
    A0 = *(const int4*)ap;
    A1 = *(const int4*)(ap + 4);
    A2 = *(const int4*)(ap + 16);
    A3 = *(const int4*)(ap + 20);
    E0 = ep[0]; E1 = ep[1]; E2 = ep[2]; E3 = ep[3];
    E4 = ep[8]; E5 = ep[9]; E6 = ep[10]; E7 = ep[11];

    acc[0] = __builtin_amdgcn_mfma_f32_32x32x16_f16(af0, B00, acc[0], 0, 0, 0);
    acc[1] = __builtin_amdgcn_mfma_f32_32x32x16_f16(af0, B01, acc[1], 0, 0, 0);
    acc[2] = __builtin_amdgcn_mfma_f32_32x32x16_f16(af0, B02, acc[2], 0, 0, 0);
    acc[3] = __builtin_amdgcn_mfma_f32_32x32x16_f16(af0, B03, acc[3], 0, 0, 0);
    acc[0] = __builtin_amdgcn_mfma_f32_32x32x16_f16(af1, B10, acc[0], 0, 0, 0);
    acc[1] = __builtin_amdgcn_mfma_f32_32x32x16_f16(af1, B11, acc[1], 0, 0, 0);
    acc[2] = __builtin_amdgcn_mfma_f32_32x32x16_f16(af1, B12, acc[2], 0, 0, 0);
    acc[3] = __builtin_amdgcn_mfma_f32_32x32x16_f16(af1, B13, acc[3], 0, 0, 0);
  }

  // partial denominator: combine kb halves; lanes 0..31 hold rows 0..31
  dloc += __shfl_xor(dloc, 32, 64);
  if (L < 32) Dws[(size_t)c * NROW + row] = dloc;

  // partial numerator: C/D layout col=L&31, row=(reg&3)+8*(reg>>2)+4*kb
  float* P = Pws + ((size_t)c * NROW + rb) * FDIM + (L & 31);
#pragma unroll
  for (int nt = 0; nt < 4; ++nt) {
#pragma unroll
    for (int reg = 0; reg < 16; ++reg) {
      int rr = (reg & 3) + 8 * (reg >> 2) + 4 * kb;
      P[(size_t)rr * FDIM + nt * 32] = acc[nt][reg];
    }
  }
}

// ---------------- k3: combine S partials, ELU ----------------
__global__ __launch_bounds__(256) void k3_comb(const float* __restrict__ Pws,
                                               const float* __restrict__ Dws,
                                               float* __restrict__ out, int S) {
  int g = (int)blockIdx.x * 256 + (int)threadIdx.x;  // 0..262143
  int r = g >> 5, f4 = g & 31;
  f32x4 s = {0.f, 0.f, 0.f, 0.f};
  float den = 0.f;
  for (int c2 = 0; c2 < S; ++c2) {
    s += *(const f32x4*)(Pws + ((size_t)c2 * NROW + r) * FDIM + f4 * 4);
    den += Dws[(size_t)c2 * NROW + r];
  }
  float inv = 1.0f / den;
  f32x4 o;
#pragma unroll
  for (int e = 0; e < 4; ++e) {
    float x = s[e] * inv;
    o[e] = x > 0.f ? x : expm1f(x);
  }
  *(f32x4*)(out + (size_t)r * FDIM + f4 * 4) = o;
}

extern "C" void kernel_launch(void* const* d_in, const int* in_sizes, int n_in,
                              void* d_out, int out_size, void* d_ws, size_t ws_size,
                              hipStream_t stream) {
  const float* h = (const float*)d_in[0];
  const int* adj = (const int*)d_in[1];
  const float* W = (const float*)d_in[2];
  const float* a = (const float*)d_in[3];
  float* out = (float*)d_out;
  char* ws = (char*)d_ws;
  f16* WhT = (f16*)(ws + WS_WHT);
  f16* Bp = (f16*)(ws + WS_BP);
  float2* s12 = (float2*)(ws + WS_S12);
  float4* RC = (float4*)(ws + WS_RC);
  float2* EF = (float2*)(ws + WS_EF);
  unsigned* M2 = (unsigned*)(ws + WS_M2);

  // S chunks of j; fall back to S=2 if workspace is small (ws_size constant across calls)
  const size_t partial_bytes = (size_t)NROW * FDIM * 4;  // 4 MiB per chunk
  int S = (ws_size >= WS_PWS + 8 * partial_bytes + 8 * NROW * 4) ? 8 : 2;
  float* Pws = (float*)(ws + WS_PWS);
  float* Dws = (float*)(ws + WS_PWS + (size_t)S * partial_bytes);
  int jspan = NROW / S;

  k1_wh<<<dim3(256), dim3(256), 0, stream>>>(h, W, WhT, Bp, M2);
  k1b_s<<<dim3(128), dim3(256), 0, stream>>>(WhT, a, s12, M2);
  k1c_prep<<<dim3(32), dim3(256), 0, stream>>>(s12, M2, RC, EF);
  k2_main<<<dim3(64 * S), dim3(256), 0, stream>>>(adj, Bp, RC, (const float*)EF, Pws, Dws, jspan);
  k3_comb<<<dim3(1024), dim3(256), 0, stream>>>(Pws, Dws, out, S);
}